// Round 1
// baseline (104.998 us; speedup 1.0000x reference)
//
#include <hip/hip_runtime.h>

#define TLEN 2048
#define BROWS 2048
#define NSHIFT 31
#define MAXSH 15
#define BLOCK 256
#define EXTN (TLEN + 2*MAXSH)   // 2078
#define EPSF 1e-8f

// padded LDS index: +2 dwords of pad per 8-float group (group stride 10)
__device__ __forceinline__ int padidx(int k) { return k + ((k >> 3) << 1); }

// smem layout:
//   phase 1: lds_t (padded ext targets) [0, 2600), lds_p (padded preds) [2600, 5160),
//            rbuf [5160, 5176), bcast [5176, 5178)
//   phase 2 (after barrier): transpose buffer [0, 31*256) = [0, 7936)
__global__ void __launch_bounds__(BLOCK)
pearson_phase_kernel(const float* __restrict__ preds,
                     const float* __restrict__ targets,
                     float* __restrict__ out)
{
    __shared__ float smem[NSHIFT * BLOCK];   // 7936 floats = 31.75 KB
    float* lds_t = smem;
    float* lds_p = smem + 2600;
    float* rbuf  = smem + 5160;
    float* bcast = smem + 5176;

    const int tid  = threadIdx.x;
    const int wave = tid >> 6;
    const int lane = tid & 63;
    const int row  = blockIdx.x;
    const float* p_row = preds   + (size_t)row * TLEN;
    const float* t_row = targets + (size_t)row * TLEN;

    // ---- Phase 1: coalesced load, row sums, stage into padded LDS ----
    float sp = 0.f, spp = 0.f, st = 0.f, stt = 0.f;
    #pragma unroll
    for (int r = 0; r < 2; ++r) {
        int f4 = tid + r * BLOCK;       // float4 index
        int m  = f4 * 4;                // logical float index (multiple of 4)
        float4 pv = ((const float4*)p_row)[f4];
        float4 tv = ((const float4*)t_row)[f4];
        sp  += pv.x + pv.y + pv.z + pv.w;
        spp += pv.x*pv.x + pv.y*pv.y + pv.z*pv.z + pv.w*pv.w;
        st  += tv.x + tv.y + tv.z + tv.w;
        stt += tv.x*tv.x + tv.y*tv.y + tv.z*tv.z + tv.w*tv.w;
        int pa = padidx(m);             // m%8 in {0,4} -> 4 floats stay in one group
        *(float2*)(lds_p + pa)     = make_float2(pv.x, pv.y);
        *(float2*)(lds_p + pa + 2) = make_float2(pv.z, pv.w);
        int k = m + MAXSH;              // ext index; may cross a group -> scalar stores
        lds_t[padidx(k)]     = tv.x;
        lds_t[padidx(k + 1)] = tv.y;
        lds_t[padidx(k + 2)] = tv.z;
        lds_t[padidx(k + 3)] = tv.w;
    }
    // halo: ext[k]=t[(k-15) mod T]
    if (tid < MAXSH) {
        lds_t[padidx(tid)] = t_row[TLEN - MAXSH + tid];
    } else if (tid >= 32 && tid < 32 + MAXSH) {
        int i = tid - 32;
        lds_t[padidx(TLEN + MAXSH + i)] = t_row[i];
    }

    // wave butterfly reduce of the 4 sums
    #pragma unroll
    for (int off = 32; off > 0; off >>= 1) {
        sp  += __shfl_xor(sp,  off);
        spp += __shfl_xor(spp, off);
        st  += __shfl_xor(st,  off);
        stt += __shfl_xor(stt, off);
    }
    if (lane == 0) {
        rbuf[wave*4 + 0] = sp;  rbuf[wave*4 + 1] = spp;
        rbuf[wave*4 + 2] = st;  rbuf[wave*4 + 3] = stt;
    }
    __syncthreads();
    if (tid == 0) {
        float SP = 0, SPP = 0, ST = 0, STT = 0;
        #pragma unroll
        for (int w2 = 0; w2 < 4; ++w2) {
            SP += rbuf[w2*4 + 0]; SPP += rbuf[w2*4 + 1];
            ST += rbuf[w2*4 + 2]; STT += rbuf[w2*4 + 3];
        }
        float mp = SP * (1.0f / TLEN), mt = ST * (1.0f / TLEN);
        float varp = SPP - (float)TLEN * mp * mp;
        float vart = STT - (float)TLEN * mt * mt;
        bcast[0] = (float)TLEN * mp * mt;                      // corr term
        bcast[1] = rsqrtf((varp + EPSF) * (vart + EPSF));      // 1/(std_p*std_t)
    }
    __syncthreads();
    const float corr    = bcast[0];
    const float inv_den = bcast[1];

    // ---- Phase 2: per-thread 8-j chunk, 38-float t-window in registers ----
    // cov_raw(s) = sum_j p[j] * ext[j + s],  s in [0,31), j chunk = [8*tid, 8*tid+8)
    float w[40];
    float pc[8];
    {
        const int base10 = 10 * tid;    // = padidx(8*tid)
        #pragma unroll
        for (int g = 0; g < 4; ++g) {
            #pragma unroll
            for (int q = 0; q < 4; ++q) {
                float2 v = *(const float2*)(lds_t + base10 + 10*g + 2*q);
                w[8*g + 2*q]     = v.x;
                w[8*g + 2*q + 1] = v.y;
            }
        }
        #pragma unroll
        for (int q = 0; q < 3; ++q) {
            float2 v = *(const float2*)(lds_t + base10 + 40 + 2*q);
            w[32 + 2*q]     = v.x;
            w[32 + 2*q + 1] = v.y;
        }
        #pragma unroll
        for (int q = 0; q < 4; ++q) {
            float2 v = *(const float2*)(lds_p + base10 + 2*q);
            pc[2*q]     = v.x;
            pc[2*q + 1] = v.y;
        }
    }
    float acc[NSHIFT];
    #pragma unroll
    for (int s = 0; s < NSHIFT; ++s) acc[s] = 0.f;
    #pragma unroll
    for (int m = 0; m < 8; ++m) {       // m outer: 31 independent FMA chains
        #pragma unroll
        for (int s = 0; s < NSHIFT; ++s) {
            acc[s] = fmaf(pc[m], w[m + s], acc[s]);
        }
    }

    // ---- reduce 31 partials across 256 threads via LDS transpose ----
    __syncthreads();                    // done reading lds_t/lds_p; safe to clobber
    #pragma unroll
    for (int s = 0; s < NSHIFT; ++s) smem[s * BLOCK + tid] = acc[s];
    __syncthreads();

    float bmax = -2.0f;
    const int s0 = wave * 8;
    const int s1 = (s0 + 8 < NSHIFT) ? s0 + 8 : NSHIFT;
    for (int s = s0; s < s1; ++s) {
        float v = smem[s*BLOCK + lane]       + smem[s*BLOCK + lane + 64]
                + smem[s*BLOCK + lane + 128] + smem[s*BLOCK + lane + 192];
        #pragma unroll
        for (int off = 32; off > 0; off >>= 1) v += __shfl_xor(v, off);
        float pear = (v - corr) * inv_den;
        bmax = fmaxf(bmax, pear);
    }
    __syncthreads();
    if (lane == 0) smem[wave] = bmax;
    __syncthreads();
    if (tid == 0) {
        float best = fmaxf(fmaxf(smem[0], smem[1]), fmaxf(smem[2], smem[3]));
        best = fmaxf(best, -1.0f);
        atomicAdd(out, (1.0f - best) * (1.0f / BROWS));
    }
}

extern "C" void kernel_launch(void* const* d_in, const int* in_sizes, int n_in,
                              void* d_out, int out_size, void* d_ws, size_t ws_size,
                              hipStream_t stream) {
    const float* preds   = (const float*)d_in[0];
    const float* targets = (const float*)d_in[1];
    float* out = (float*)d_out;
    hipMemsetAsync(out, 0, sizeof(float), stream);   // out is re-poisoned each launch
    pearson_phase_kernel<<<BROWS, BLOCK, 0, stream>>>(preds, targets, out);
}

// Round 2
// 85.117 us; speedup vs baseline: 1.2336x; 1.2336x over previous
//
#include <hip/hip_runtime.h>

#define TLEN 2048
#define BROWS 2048
#define NSHIFT 31
#define MAXSH 15
#define BLOCK 256
#define EPSF 1e-8f

// padded LDS index for staged ext-targets: +2 dwords of pad per 8-float group
// (group stride 10 dwords -> 16 distinct even start-banks across a wave,
//  uniform 4 accesses/bank for b64 reads = minimal)
__device__ __forceinline__ int padidx(int k) { return k + ((k >> 3) << 1); }

// smem layout (floats):
//   [0, 7936)        : phase A = padded ext targets (needs 2596) ; phase B = 31x256 transpose
//   [7936, 7952)     : rbuf  (4 waves x 4 row-sums)  -- survives both phases
//   [7952, 7956)     : wmax  (per-wave max of raw dots)
__global__ void __launch_bounds__(BLOCK, 4)
pearson_rows_kernel(const float* __restrict__ preds,
                    const float* __restrict__ targets,
                    float* __restrict__ row_best)
{
    __shared__ float smem[NSHIFT * BLOCK + 20];
    float* rbuf = smem + NSHIFT * BLOCK;
    float* wmax = rbuf + 16;

    const int tid  = threadIdx.x;
    const int wave = tid >> 6;
    const int lane = tid & 63;
    const int row  = blockIdx.x;
    const float* p_row = preds   + (size_t)row * TLEN;
    const float* t_row = targets + (size_t)row * TLEN;

    // ---- p: global -> registers directly (thread owns j in [8*tid, 8*tid+8)) ----
    float pc[8];
    {
        float4 a = ((const float4*)p_row)[2 * tid];
        float4 b = ((const float4*)p_row)[2 * tid + 1];
        pc[0] = a.x; pc[1] = a.y; pc[2] = a.z; pc[3] = a.w;
        pc[4] = b.x; pc[5] = b.y; pc[6] = b.z; pc[7] = b.w;
    }
    float sp = 0.f, spp = 0.f;
    #pragma unroll
    for (int i = 0; i < 8; ++i) { sp += pc[i]; spp = fmaf(pc[i], pc[i], spp); }

    // ---- t: coalesced load, row sums, stage ext into padded LDS ----
    float st = 0.f, stt = 0.f;
    #pragma unroll
    for (int r = 0; r < 2; ++r) {
        int f4 = tid + r * BLOCK;
        float4 tv = ((const float4*)t_row)[f4];
        st  += tv.x + tv.y + tv.z + tv.w;
        stt = fmaf(tv.x, tv.x, stt); stt = fmaf(tv.y, tv.y, stt);
        stt = fmaf(tv.z, tv.z, stt); stt = fmaf(tv.w, tv.w, stt);
        int k = f4 * 4 + MAXSH;          // ext index: ext[k] = t[(k-15) mod T]
        smem[padidx(k)]     = tv.x;
        smem[padidx(k + 1)] = tv.y;
        smem[padidx(k + 2)] = tv.z;
        smem[padidx(k + 3)] = tv.w;
    }
    if (tid < MAXSH) {
        smem[padidx(tid)] = t_row[TLEN - MAXSH + tid];
    } else if (tid >= 32 && tid < 32 + MAXSH) {
        int i = tid - 32;
        smem[padidx(TLEN + MAXSH + i)] = t_row[i];
    }

    // wave butterfly reduce of the 4 row sums (needed only by the final thread)
    #pragma unroll
    for (int off = 32; off > 0; off >>= 1) {
        sp  += __shfl_xor(sp,  off);
        spp += __shfl_xor(spp, off);
        st  += __shfl_xor(st,  off);
        stt += __shfl_xor(stt, off);
    }
    if (lane == 0) {
        rbuf[wave * 4 + 0] = sp;  rbuf[wave * 4 + 1] = spp;
        rbuf[wave * 4 + 2] = st;  rbuf[wave * 4 + 3] = stt;
    }
    __syncthreads();   // staging (and rbuf) visible

    // ---- sliding-window reads: padded offset of ext[8*tid + d] = 10*tid + d + 2*(d>>3) ----
    float w[38];
    {
        const int base = 10 * tid;
        #pragma unroll
        for (int q = 0; q < 19; ++q) {
            int d = 2 * q;               // even, never crosses a pad group (d%8 != 7)
            float2 v = *(const float2*)(smem + base + d + 2 * (d >> 3));
            w[d]     = v.x;
            w[d + 1] = v.y;
        }
    }
    __syncthreads();   // all window reads done before transpose clobbers smem

    // ---- 31 raw circular dots: acc[s] = sum_m pc[m] * ext[8*tid + m + s] ----
    float acc[NSHIFT];
    #pragma unroll
    for (int s = 0; s < NSHIFT; ++s) acc[s] = 0.f;
    #pragma unroll
    for (int m = 0; m < 8; ++m) {
        #pragma unroll
        for (int s = 0; s < NSHIFT; ++s) acc[s] = fmaf(pc[m], w[m + s], acc[s]);
    }

    // ---- reduce 31 partials across 256 threads: transpose + per-wave butterfly ----
    #pragma unroll
    for (int s = 0; s < NSHIFT; ++s) smem[s * BLOCK + tid] = acc[s];
    __syncthreads();

    float dmax = -1e30f;
    const int s0 = wave * 8;
    const int s1 = (s0 + 8 < NSHIFT) ? s0 + 8 : NSHIFT;
    for (int s = s0; s < s1; ++s) {
        float v = smem[s * BLOCK + lane]       + smem[s * BLOCK + lane + 64]
                + smem[s * BLOCK + lane + 128] + smem[s * BLOCK + lane + 192];
        #pragma unroll
        for (int off = 32; off > 0; off >>= 1) v += __shfl_xor(v, off);
        dmax = fmaxf(dmax, v);           // butterfly -> all lanes hold the total
    }
    if (lane == 0) wmax[wave] = dmax;
    __syncthreads();

    // ---- final: max over shifts commutes with the (positive-scale) affine map ----
    if (tid == 0) {
        float dot = fmaxf(fmaxf(wmax[0], wmax[1]), fmaxf(wmax[2], wmax[3]));
        float SP = 0, SPP = 0, ST = 0, STT = 0;
        #pragma unroll
        for (int w2 = 0; w2 < 4; ++w2) {
            SP += rbuf[w2 * 4 + 0]; SPP += rbuf[w2 * 4 + 1];
            ST += rbuf[w2 * 4 + 2]; STT += rbuf[w2 * 4 + 3];
        }
        const float invT = 1.0f / TLEN;
        float mp = SP * invT, mt = ST * invT;
        float varp = SPP - (float)TLEN * mp * mp;
        float vart = STT - (float)TLEN * mt * mt;
        float corr = (float)TLEN * mp * mt;
        float pear = (dot - corr) * rsqrtf((varp + EPSF) * (vart + EPSF));
        row_best[row] = fmaxf(pear, -1.0f);
    }
}

// 1 block: mean over 2048 per-row bests, write final loss (no init of out needed)
__global__ void __launch_bounds__(BLOCK)
pearson_finalize_kernel(const float* __restrict__ row_best, float* __restrict__ out)
{
    __shared__ float r[4];
    const int tid = threadIdx.x, wave = tid >> 6, lane = tid & 63;
    float s = 0.f;
    #pragma unroll
    for (int i = 0; i < 8; ++i) s += row_best[tid + i * BLOCK];
    #pragma unroll
    for (int off = 32; off > 0; off >>= 1) s += __shfl_xor(s, off);
    if (lane == 0) r[wave] = s;
    __syncthreads();
    if (tid == 0)
        out[0] = 1.0f - (r[0] + r[1] + r[2] + r[3]) * (1.0f / (float)BROWS);
}

extern "C" void kernel_launch(void* const* d_in, const int* in_sizes, int n_in,
                              void* d_out, int out_size, void* d_ws, size_t ws_size,
                              hipStream_t stream) {
    const float* preds   = (const float*)d_in[0];
    const float* targets = (const float*)d_in[1];
    float* row_best = (float*)d_ws;          // 2048 floats of scratch
    float* out      = (float*)d_out;
    pearson_rows_kernel<<<BROWS, BLOCK, 0, stream>>>(preds, targets, row_best);
    pearson_finalize_kernel<<<1, BLOCK, 0, stream>>>(row_best, out);
}